// Round 1
// baseline (480.013 us; speedup 1.0000x reference)
//
#include <hip/hip_runtime.h>

typedef unsigned short u16;
typedef unsigned int u32;
typedef short bf16x8 __attribute__((ext_vector_type(8)));
typedef float f32x4 __attribute__((ext_vector_type(4)));

#define AS1 __attribute__((address_space(1)))
#define AS3 __attribute__((address_space(3)))

#define B_ 2
#define T_ 2048
#define DIM_ 1024
#define HID_ 4096
#define H_ 16
#define KVH_ 4
#define HD_ 64
#define WIN_ 512

__device__ __forceinline__ u16 f2bf(float f) {
    union { float f; u32 u; } v; v.f = f;
    u32 r = v.u + 0x7FFFu + ((v.u >> 16) & 1u);
    return (u16)(r >> 16);
}
__device__ __forceinline__ float bf2f(u16 u) {
    union { u32 u; float f; } v; v.u = ((u32)u) << 16;
    return v.f;
}
__device__ __forceinline__ void load_lds16(const void* g, void* l) {
    __builtin_amdgcn_global_load_lds((AS1 void*)(g), (AS3 void*)(l), 16, 0, 0);
}

// ---------------- fp32 -> bf16 weight convert ----------------
__global__ __launch_bounds__(256) void cvt_kernel(const float* __restrict__ s,
                                                  u16* __restrict__ d, int n4) {
    int i = blockIdx.x * 256 + threadIdx.x;
    if (i < n4) {
        float4 v = ((const float4*)s)[i];
        u32 lo = (u32)f2bf(v.x) | ((u32)f2bf(v.y) << 16);
        u32 hi = (u32)f2bf(v.z) | ((u32)f2bf(v.w) << 16);
        ((uint2*)d)[i] = make_uint2(lo, hi);
    }
}

// ---------------- RMSNorm (fp32 in, bf16 out), dim=1024 ----------------
__global__ __launch_bounds__(256) void rmsnorm_kernel(const float* __restrict__ x,
                                                      const float* __restrict__ w,
                                                      u16* __restrict__ out, float eps) {
    int row = blockIdx.x, tid = threadIdx.x;
    const float4 v = ((const float4*)(x + (size_t)row * DIM_))[tid];
    float ss = v.x * v.x + v.y * v.y + v.z * v.z + v.w * v.w;
#pragma unroll
    for (int m = 1; m < 64; m <<= 1) ss += __shfl_xor(ss, m);
    __shared__ float part[4];
    if ((tid & 63) == 0) part[tid >> 6] = ss;
    __syncthreads();
    float tot = part[0] + part[1] + part[2] + part[3];
    float r = rsqrtf(tot * (1.0f / DIM_) + eps);
    const float4 wv = ((const float4*)w)[tid];
    u32 lo = (u32)f2bf(v.x * r * wv.x) | ((u32)f2bf(v.y * r * wv.y) << 16);
    u32 hi = (u32)f2bf(v.z * r * wv.z) | ((u32)f2bf(v.w * r * wv.w) << 16);
    ((uint2*)(out + (size_t)row * DIM_))[tid] = make_uint2(lo, hi);
}

// ---------------- QKV post: per-head RMSNorm(eps 1e-6) + bf16 pack ----------------
// qkv: [B*T][1536] fp32 (q 0..1023, k 1024..1279, v 1280..1535)
// Qb: [B][H][T][64], Kb/Vb: [B][KVH][T][64]
__global__ __launch_bounds__(256) void qkv_post_kernel(const float* __restrict__ qkv,
                                                       const float* __restrict__ qw,
                                                       const float* __restrict__ kw,
                                                       u16* __restrict__ Qb,
                                                       u16* __restrict__ Kb,
                                                       u16* __restrict__ Vb) {
    int bt = blockIdx.x;
    int b = bt >> 11, t = bt & (T_ - 1);
    int wave = threadIdx.x >> 6, lane = threadIdx.x & 63;
    const float* row = qkv + (size_t)bt * 1536;
    float qwl = qw[lane], kwl = kw[lane];
#pragma unroll
    for (int i = 0; i < 4; i++) {
        int h = wave * 4 + i;
        float v = row[h * 64 + lane];
        float ss = v * v;
#pragma unroll
        for (int m = 1; m < 64; m <<= 1) ss += __shfl_xor(ss, m);
        float r = rsqrtf(ss * (1.0f / 64.0f) + 1e-6f);
        Qb[(((size_t)(b * H_ + h)) * T_ + t) * HD_ + lane] = f2bf(v * r * qwl);
    }
    {
        float v = row[1024 + wave * 64 + lane];
        float ss = v * v;
#pragma unroll
        for (int m = 1; m < 64; m <<= 1) ss += __shfl_xor(ss, m);
        float r = rsqrtf(ss * (1.0f / 64.0f) + 1e-6f);
        Kb[(((size_t)(b * KVH_ + wave)) * T_ + t) * HD_ + lane] = f2bf(v * r * kwl);
        float vv = row[1280 + wave * 64 + lane];
        Vb[(((size_t)(b * KVH_ + wave)) * T_ + t) * HD_ + lane] = f2bf(vv);
    }
}

// ---------------- Flash attention, sliding window 512, GQA 16/4 ----------------
// grid (T/64, H, B), block 256. Wave w handles q rows [q0+16w, q0+16w+15].
__global__ __launch_bounds__(256) void flash_kernel(const u16* __restrict__ Qb,
                                                    const u16* __restrict__ Kb,
                                                    const u16* __restrict__ Vb,
                                                    u16* __restrict__ Ob) {
    const int b = blockIdx.z, h = blockIdx.y, qt = blockIdx.x;
    const int q0 = qt * 64;
    const int tid = threadIdx.x, wave = tid >> 6, lane = tid & 63;
    const int m = lane & 15, quad = lane >> 4;
    const int kvh = h >> 2;

    __shared__ __align__(16) u16 Ks[32 * 64];   // [k][d]
    __shared__ __align__(16) u16 Vts[64 * 32];  // [d][k]
    __shared__ __align__(16) u16 Ps[4][16 * 32]; // per-wave P tile [q][k]

    const u16* Qp = Qb + ((size_t)(b * H_ + h) * T_) * HD_;
    const u16* Kp = Kb + ((size_t)(b * KVH_ + kvh) * T_) * HD_;
    const u16* Vp = Vb + ((size_t)(b * KVH_ + kvh) * T_) * HD_;

    const int qrow = q0 + wave * 16 + m;
    bf16x8 qa0 = *(const bf16x8*)(Qp + (size_t)qrow * 64 + quad * 8);
    bf16x8 qa1 = *(const bf16x8*)(Qp + (size_t)qrow * 64 + 32 + quad * 8);

    f32x4 o0 = {0.f, 0.f, 0.f, 0.f}, o1 = {0.f, 0.f, 0.f, 0.f};
    f32x4 o2 = {0.f, 0.f, 0.f, 0.f}, o3 = {0.f, 0.f, 0.f, 0.f};
    float mrun[4] = {-INFINITY, -INFINITY, -INFINITY, -INFINITY};
    float lrun[4] = {0.f, 0.f, 0.f, 0.f};

    const int klo = (q0 - (WIN_ - 1) > 0) ? (q0 - (WIN_ - 1)) : 0;
    const int kt0 = klo >> 5, kt1 = (q0 + 63) >> 5;
    const int qlo_w = q0 + wave * 16, qhi_w = qlo_w + 15;

    for (int kt = kt0; kt <= kt1; ++kt) {
        const int kbase = kt << 5;
        __syncthreads();
        {   // stage K [32][64] and V transposed [64][32]
            int flat = tid * 8;
            int kr = flat >> 6, d = flat & 63;
            *(bf16x8*)&Ks[flat] = *(const bf16x8*)(Kp + (size_t)(kbase + kr) * 64 + d);
            bf16x8 vv = *(const bf16x8*)(Vp + (size_t)(kbase + kr) * 64 + d);
#pragma unroll
            for (int jj = 0; jj < 8; jj++) Vts[(d + jj) * 32 + kr] = (u16)vv[jj];
        }
        __syncthreads();
        bool active = (kbase <= qhi_w) && (kbase + 31 >= qlo_w - (WIN_ - 1));
        if (active) {
            f32x4 s0 = {0.f, 0.f, 0.f, 0.f}, s1 = {0.f, 0.f, 0.f, 0.f};
            bf16x8 k00 = *(const bf16x8*)&Ks[m * 64 + quad * 8];
            bf16x8 k01 = *(const bf16x8*)&Ks[m * 64 + 32 + quad * 8];
            bf16x8 k10 = *(const bf16x8*)&Ks[(m + 16) * 64 + quad * 8];
            bf16x8 k11 = *(const bf16x8*)&Ks[(m + 16) * 64 + 32 + quad * 8];
            s0 = __builtin_amdgcn_mfma_f32_16x16x32_bf16(qa0, k00, s0, 0, 0, 0);
            s0 = __builtin_amdgcn_mfma_f32_16x16x32_bf16(qa1, k01, s0, 0, 0, 0);
            s1 = __builtin_amdgcn_mfma_f32_16x16x32_bf16(qa0, k10, s1, 0, 0, 0);
            s1 = __builtin_amdgcn_mfma_f32_16x16x32_bf16(qa1, k11, s1, 0, 0, 0);
#pragma unroll
            for (int r = 0; r < 4; r++) {
                int qg = q0 + wave * 16 + quad * 4 + r;
                int kg0 = kbase + m, kg1 = kbase + 16 + m;
                float v0 = (kg0 <= qg && qg - kg0 < WIN_) ? s0[r] * 0.125f : -INFINITY;
                float v1 = (kg1 <= qg && qg - kg1 < WIN_) ? s1[r] * 0.125f : -INFINITY;
                float rmax = fmaxf(v0, v1);
                rmax = fmaxf(rmax, __shfl_xor(rmax, 1));
                rmax = fmaxf(rmax, __shfl_xor(rmax, 2));
                rmax = fmaxf(rmax, __shfl_xor(rmax, 4));
                rmax = fmaxf(rmax, __shfl_xor(rmax, 8));
                float mnew = fmaxf(mrun[r], rmax);
                float alpha, p0, p1;
                if (mnew == -INFINITY) { alpha = 1.f; p0 = 0.f; p1 = 0.f; }
                else {
                    alpha = __expf(mrun[r] - mnew);  // exp(-inf)=0 ok
                    p0 = __expf(v0 - mnew);          // v0=-inf -> 0
                    p1 = __expf(v1 - mnew);
                }
                float psum = p0 + p1;
                psum += __shfl_xor(psum, 1);
                psum += __shfl_xor(psum, 2);
                psum += __shfl_xor(psum, 4);
                psum += __shfl_xor(psum, 8);
                lrun[r] = lrun[r] * alpha + psum;
                mrun[r] = mnew;
                o0[r] *= alpha; o1[r] *= alpha; o2[r] *= alpha; o3[r] *= alpha;
                Ps[wave][(quad * 4 + r) * 32 + m] = f2bf(p0);
                Ps[wave][(quad * 4 + r) * 32 + 16 + m] = f2bf(p1);
            }
            // PV: A = P (A-layout via LDS), B = V via Vts
            bf16x8 pa = *(const bf16x8*)&Ps[wave][m * 32 + quad * 8];
            bf16x8 vb0 = *(const bf16x8*)&Vts[(0 + m) * 32 + quad * 8];
            bf16x8 vb1 = *(const bf16x8*)&Vts[(16 + m) * 32 + quad * 8];
            bf16x8 vb2 = *(const bf16x8*)&Vts[(32 + m) * 32 + quad * 8];
            bf16x8 vb3 = *(const bf16x8*)&Vts[(48 + m) * 32 + quad * 8];
            o0 = __builtin_amdgcn_mfma_f32_16x16x32_bf16(pa, vb0, o0, 0, 0, 0);
            o1 = __builtin_amdgcn_mfma_f32_16x16x32_bf16(pa, vb1, o1, 0, 0, 0);
            o2 = __builtin_amdgcn_mfma_f32_16x16x32_bf16(pa, vb2, o2, 0, 0, 0);
            o3 = __builtin_amdgcn_mfma_f32_16x16x32_bf16(pa, vb3, o3, 0, 0, 0);
        }
    }
#pragma unroll
    for (int r = 0; r < 4; r++) {
        int qg = q0 + wave * 16 + quad * 4 + r;
        float inv = 1.0f / lrun[r];
        size_t base = ((size_t)(b * T_ + qg)) * (H_ * HD_) + h * HD_;
        Ob[base + 0 + m] = f2bf(o0[r] * inv);
        Ob[base + 16 + m] = f2bf(o1[r] * inv);
        Ob[base + 32 + m] = f2bf(o2[r] * inv);
        Ob[base + 48 + m] = f2bf(o3[r] * inv);
    }
}

// ---------------- GEMM: C[M][N] = A[M][K] * Bt[N][K]^T (m97 structure) ----------------
// MODE 0: Cf = acc (fp32). MODE 1: Cf = resid + acc*scale[col]. MODE 2: Cb = bf16(acc).
template <int MODE>
__global__ __launch_bounds__(256) void gemm_bt(const u16* __restrict__ A,
                                               const u16* __restrict__ Bt,
                                               float* __restrict__ Cf,
                                               u16* __restrict__ Cb,
                                               const float* __restrict__ resid,
                                               const float* __restrict__ scale,
                                               int M, int N, int K) {
    __shared__ __align__(16) u16 As[128 * 32];
    __shared__ __align__(16) u16 Bs[128 * 32];
    const int tid = threadIdx.x, wave = tid >> 6, lane = tid & 63;
    const int m = lane & 15, quad = lane >> 4;
    const int m0 = blockIdx.y * 128, n0 = blockIdx.x * 128;
    const int wm = (wave >> 1) * 64, wn = (wave & 1) * 64;

    f32x4 acc[4][4] = {};

    for (int k0 = 0; k0 < K; k0 += 32) {
        __syncthreads();
#pragma unroll
        for (int j = 0; j < 2; j++) {
            int slot = wave * 2 + j;                 // 0..7
            int flat = slot * 512 + lane * 8;
            int row = flat >> 5, col = flat & 31;
            load_lds16(A + (size_t)(m0 + row) * K + k0 + col, &As[slot * 512]);
            load_lds16(Bt + (size_t)(n0 + row) * K + k0 + col, &Bs[slot * 512]);
        }
        __syncthreads();
        bf16x8 af[4], bfr[4];
#pragma unroll
        for (int i = 0; i < 4; i++) af[i] = *(const bf16x8*)&As[(wm + i * 16 + m) * 32 + quad * 8];
#pragma unroll
        for (int j = 0; j < 4; j++) bfr[j] = *(const bf16x8*)&Bs[(wn + j * 16 + m) * 32 + quad * 8];
#pragma unroll
        for (int i = 0; i < 4; i++)
#pragma unroll
            for (int j = 0; j < 4; j++)
                acc[i][j] = __builtin_amdgcn_mfma_f32_16x16x32_bf16(af[i], bfr[j], acc[i][j], 0, 0, 0);
    }

#pragma unroll
    for (int i = 0; i < 4; i++) {
        int rowb = m0 + wm + i * 16 + quad * 4;
#pragma unroll
        for (int j = 0; j < 4; j++) {
            int col = n0 + wn + j * 16 + m;
            float sc = (MODE == 1) ? scale[col] : 0.f;
#pragma unroll
            for (int r = 0; r < 4; r++) {
                size_t idx = (size_t)(rowb + r) * N + col;
                float v = acc[i][j][r];
                if (MODE == 0) Cf[idx] = v;
                else if (MODE == 1) Cf[idx] = resid[idx] + v * sc;
                else Cb[idx] = f2bf(v);
            }
        }
    }
}

// ---------------- SwiGLU: out[i][j] = bf16( silu(g[i][j]) * g[i][j+4096] ) ----------------
__global__ __launch_bounds__(256) void swiglu_kernel(const u16* __restrict__ g,
                                                     u16* __restrict__ out) {
    int idx = blockIdx.x * 256 + threadIdx.x;  // 0 .. 4096*512-1
    int row = idx >> 9, cg = idx & 511;
    const u16* gr = g + (size_t)row * (2 * HID_) + cg * 8;
    bf16x8 a = *(const bf16x8*)gr;
    bf16x8 c = *(const bf16x8*)(gr + HID_);
    bf16x8 o;
#pragma unroll
    for (int i = 0; i < 8; i++) {
        float xx = bf2f((u16)a[i]);
        float yy = bf2f((u16)c[i]);
        float s = xx / (1.f + __expf(-xx));
        o[i] = (short)f2bf(s * yy);
    }
    *(bf16x8*)(out + (size_t)row * HID_ + cg * 8) = o;
}

extern "C" void kernel_launch(void* const* d_in, const int* in_sizes, int n_in,
                              void* d_out, int out_size, void* d_ws, size_t ws_size,
                              hipStream_t stream) {
    const float* x = (const float*)d_in[0];
    const float* wq = (const float*)d_in[1];
    const float* wk = (const float*)d_in[2];
    const float* wv = (const float*)d_in[3];
    const float* wo = (const float*)d_in[4];
    const float* w1 = (const float*)d_in[5];
    const float* w2 = (const float*)d_in[6];
    const float* w3 = (const float*)d_in[7];
    const float* qnw = (const float*)d_in[8];
    const float* knw = (const float*)d_in[9];
    const float* anw = (const float*)d_in[10];
    const float* fnw = (const float*)d_in[11];
    const float* ascale = (const float*)d_in[12];
    const float* fscale = (const float*)d_in[13];
    float* out = (float*)d_out;

    // ---- workspace layout (total 156,237,824 B ~= 149 MiB), buffer reuse overlay ----
    char* ws = (char*)d_ws;
    u16* wqkv_bf = (u16*)(ws + 0);             // [1536][1024] bf16 (wq|wk|wv)
    u16* wo_bf = (u16*)(ws + 3145728);         // [1024][1024]
    u16* w13_bf = (u16*)(ws + 5242880);        // [8192][1024] (w1|w3)
    u16* w2_bf = (u16*)(ws + 22020096);        // [1024][4096]
    u16* xn_bf = (u16*)(ws + 30408704);        // [4096][1024], reused for hn
    char* pool = ws + 38797312;                // 64 MiB pool
    float* qkv_f = (float*)(pool + 0);         // [4096][1536] fp32
    u16* Qb = (u16*)(pool + 25165824);         // [2][16][2048][64]
    u16* Kb = (u16*)(pool + 33554432);         // [2][4][2048][64]
    u16* Vb = (u16*)(pool + 35651584);         // [2][4][2048][64]
    u16* att_bf = (u16*)(pool + 37748736);     // [4096][1024]
    u16* g_bf = (u16*)(pool + 0);              // [4096][8192] (reuses pool after attention)
    float* h_f = (float*)(ws + 105906176);     // [4096][1024] fp32
    u16* gsw_bf = (u16*)(ws + 122683392);      // [4096][4096]

    // 1. weight converts (fp32 -> bf16, stacked)
    cvt_kernel<<<1024, 256, 0, stream>>>(wq, wqkv_bf, 262144);
    cvt_kernel<<<256, 256, 0, stream>>>(wk, wqkv_bf + 1048576, 65536);
    cvt_kernel<<<256, 256, 0, stream>>>(wv, wqkv_bf + 1310720, 65536);
    cvt_kernel<<<1024, 256, 0, stream>>>(wo, wo_bf, 262144);
    cvt_kernel<<<4096, 256, 0, stream>>>(w1, w13_bf, 1048576);
    cvt_kernel<<<4096, 256, 0, stream>>>(w3, w13_bf + 4194304, 1048576);
    cvt_kernel<<<4096, 256, 0, stream>>>(w2, w2_bf, 1048576);

    // 2. attn-input RMSNorm
    rmsnorm_kernel<<<4096, 256, 0, stream>>>(x, anw, xn_bf, 1e-5f);
    // 3. QKV projection
    gemm_bt<0><<<dim3(12, 32), 256, 0, stream>>>(xn_bf, wqkv_bf, qkv_f, nullptr,
                                                 nullptr, nullptr, 4096, 1536, 1024);
    // 4. QK norm + pack
    qkv_post_kernel<<<4096, 256, 0, stream>>>(qkv_f, qnw, knw, Qb, Kb, Vb);
    // 5. sliding-window flash attention
    flash_kernel<<<dim3(32, 16, 2), 256, 0, stream>>>(Qb, Kb, Vb, att_bf);
    // 6. out-proj + residual layer-scale: h = x + r*attn_scale
    gemm_bt<1><<<dim3(8, 32), 256, 0, stream>>>(att_bf, wo_bf, h_f, nullptr,
                                                x, ascale, 4096, 1024, 1024);
    // 7. ffn-input RMSNorm
    rmsnorm_kernel<<<4096, 256, 0, stream>>>(h_f, fnw, xn_bf, 1e-5f);
    // 8. w1|w3 projection (bf16 out)
    gemm_bt<2><<<dim3(64, 32), 256, 0, stream>>>(xn_bf, w13_bf, nullptr, g_bf,
                                                 nullptr, nullptr, 4096, 8192, 1024);
    // 9. SwiGLU
    swiglu_kernel<<<8192, 256, 0, stream>>>(g_bf, gsw_bf);
    // 10. w2 projection + residual layer-scale: out = h + ffn*ffn_scale
    gemm_bt<1><<<dim3(8, 32), 256, 0, stream>>>(gsw_bf, w2_bf, out, nullptr,
                                                h_f, fscale, 4096, 1024, 4096);
}